// Round 8
// baseline (243.237 us; speedup 1.0000x reference)
//
#include <hip/hip_runtime.h>

#define N_NODES 100000
#define N_EDGES 640000
#define D 128
#define NB ((N_NODES + 1023) / 1024)   // 98 scan blocks
#define BKT_C 16                        // bucket capacity: 16 ints = one 64B line
#define OVF_CAP 16384
// 2-D histogram: 16 node-ranges x 8 edge-slices
#define NRG 16
#define NRN (N_NODES / NRG)             // 6250 nodes per range (exact)
#define NSL 8
#define ESL (N_EDGES / NSL)             // 80000 edges per slice (exact)

typedef short v8s __attribute__((ext_vector_type(8)));
typedef float v4f __attribute__((ext_vector_type(4)));

__device__ __forceinline__ unsigned short f2bf(float x) {
    unsigned int u = __builtin_bit_cast(unsigned int, x);
    u += 0x7fffu + ((u >> 16) & 1u);   // RNE
    return (unsigned short)(u >> 16);
}
__device__ __forceinline__ float bf2f(unsigned int hi) {
    return __builtin_bit_cast(float, hi << 16);
}

// ---------------------------------------------------------------------------
// k_zero: zero pk[N] + ovf_cnt
// ---------------------------------------------------------------------------
__global__ __launch_bounds__(256) void k_zero(int4* __restrict__ pk4,
                                              int* __restrict__ ovf_cnt) {
    int i = blockIdx.x * blockDim.x + threadIdx.x;
    if (i < N_NODES / 4) pk4[i] = make_int4(0, 0, 0, 0);
    if (i == 0) *ovf_cnt = 0;
}

// ---------------------------------------------------------------------------
// k_hist: block (r,sl) scans edge slice sl and LDS-histograms (u32 bins,
// 25 KB) only nodes in range r. Partials dumped with coalesced stores.
// Zero global atomics; bins are u32 so no overflow possible.
// ---------------------------------------------------------------------------
__global__ __launch_bounds__(1024) void k_hist(const int* __restrict__ src,
                                               unsigned int* __restrict__ partials) {
    __shared__ unsigned int h[NRN];    // 25 KB
    int tid = threadIdx.x;
    int r = blockIdx.x / NSL;
    int sl = blockIdx.x % NSL;
    for (int i = tid; i < NRN; i += 1024) h[i] = 0;
    __syncthreads();
    int n0 = r * NRN;
    int e0 = sl * ESL;
    for (int i = tid; i < ESL; i += 1024) {
        unsigned int rel = (unsigned int)(src[e0 + i] - n0);
        if (rel < NRN) atomicAdd(&h[rel], 1u);   // LDS atomic, cheap
    }
    __syncthreads();
    unsigned int* dp = partials + (size_t)blockIdx.x * NRN;
    for (int i = tid; i < NRN; i += 1024) dp[i] = h[i];
}

// ---------------------------------------------------------------------------
// k_comb: dis[n] = deg_src>0 ? deg^-0.5 : 0, summing the NSL slice partials.
// ---------------------------------------------------------------------------
__global__ __launch_bounds__(256) void k_comb(const unsigned int* __restrict__ partials,
                                              float* __restrict__ dis) {
    int n = blockIdx.x * blockDim.x + threadIdx.x;
    if (n >= N_NODES) return;
    int r = n / NRN;
    int rel = n - r * NRN;
    unsigned int a = 0;
#pragma unroll
    for (int sl = 0; sl < NSL; sl++)
        a += partials[(size_t)(r * NSL + sl) * NRN + rel];
    dis[n] = (a > 0) ? rsqrtf((float)a) : 0.0f;
}

// ---------------------------------------------------------------------------
// k_pre: featsh bf16 pack into SECOND 256B of each 512B d_out row; weights ->
// Bcat bf16; bias=bm+bs. Path A (bucket!=null): ONE atomic per edge — the
// bucket-slot claim on pk[dst]; src goes straight into the 16-entry bucket
// line (overflow -> tiny ovf list). Path B (fallback): packed dual counts.
// ---------------------------------------------------------------------------
__global__ __launch_bounds__(256) void k_pre(const float* __restrict__ feats,
                                             const float* __restrict__ Wm,
                                             const float* __restrict__ Ws,
                                             const float* __restrict__ bmsg,
                                             const float* __restrict__ bskip,
                                             const int* __restrict__ src,
                                             const int* __restrict__ dst,
                                             unsigned int* __restrict__ pk,
                                             unsigned short* __restrict__ Bcat,
                                             float* __restrict__ bias,
                                             char* __restrict__ outb,
                                             int* __restrict__ bucket,
                                             int* __restrict__ ovf_cnt,
                                             int2* __restrict__ ovf) {
    int i = blockIdx.x * blockDim.x + threadIdx.x;
    if (i < D * D) {
        int j = i >> 7;
        int k = i & 127;
        Bcat[j * 256 + k]       = f2bf(Wm[i]);
        Bcat[j * 256 + 128 + k] = f2bf(Ws[i]);
    }
    if (i < D) bias[i] = bmsg[i] + bskip[i];
    if (i < N_EDGES) {
        int s = src[i];
        int d = dst[i];
        if (bucket) {
            unsigned int p = atomicAdd(&pk[d], 1u);
            if (p < BKT_C) {
                bucket[d * BKT_C + (int)p] = s;
            } else {
                int q = atomicAdd(ovf_cnt, 1);
                if (q < OVF_CAP) ovf[q] = make_int2(d, s);
            }
        } else {
            atomicAdd(&pk[s], 1u);
            atomicAdd(&pk[d], 0x10000u);
        }
    }
    int g = i * 8;
    int row = g >> 7;
    int col = g & 127;
    if (row < N_NODES) {
        const float4* sp = (const float4*)(feats + g);
        float4 x = sp[0], y = sp[1];
        uint4 p;
        p.x = (unsigned)f2bf(x.x) | ((unsigned)f2bf(x.y) << 16);
        p.y = (unsigned)f2bf(x.z) | ((unsigned)f2bf(x.w) << 16);
        p.z = (unsigned)f2bf(y.x) | ((unsigned)f2bf(y.y) << 16);
        p.w = (unsigned)f2bf(y.z) | ((unsigned)f2bf(y.w) << 16);
        *(uint4*)(outb + (size_t)row * 512 + 256 + col * 2) = p;
    }
}

// ---------------------------------------------------------------------------
// Path B fallback: exclusive scan of cnt_dst (pk hi16) -> rowptr, then fill.
// ---------------------------------------------------------------------------
__global__ __launch_bounds__(256) void k_scan1(const unsigned int* __restrict__ pk,
                                               int* __restrict__ rowptr,
                                               int* __restrict__ bsums) {
    __shared__ int sd[256];
    int t = threadIdx.x;
    int i0 = blockIdx.x * 1024 + t * 4;
    int v[4];
    int s = 0;
#pragma unroll
    for (int q = 0; q < 4; q++) {
        int i = i0 + q;
        v[q] = (i < N_NODES) ? (int)(pk[i] >> 16) : 0;
        s += v[q];
    }
    sd[t] = s;
    __syncthreads();
    for (int off = 1; off < 256; off <<= 1) {
        int y = (t >= off) ? sd[t - off] : 0;
        __syncthreads();
        sd[t] += y;
        __syncthreads();
    }
    int run = sd[t] - s;
    if (t == 255) bsums[blockIdx.x] = sd[255];
#pragma unroll
    for (int q = 0; q < 4; q++) {
        int i = i0 + q;
        if (i < N_NODES) rowptr[i] = run;
        run += v[q];
    }
}

__global__ __launch_bounds__(128) void k_scan2(int* __restrict__ bsums) {
    __shared__ int sd[128];
    int t = threadIdx.x;
    int v = (t < NB) ? bsums[t] : 0;
    sd[t] = v;
    __syncthreads();
    for (int off = 1; off < 128; off <<= 1) {
        int y = (t >= off) ? sd[t - off] : 0;
        __syncthreads();
        sd[t] += y;
        __syncthreads();
    }
    if (t < NB) bsums[t] = sd[t] - v;
}

__global__ __launch_bounds__(256) void k_scan3(const int* __restrict__ bsums,
                                               int* __restrict__ rowptr) {
    int add = bsums[blockIdx.x];
    int i0 = blockIdx.x * 1024 + threadIdx.x * 4;
#pragma unroll
    for (int q = 0; q < 4; q++) {
        int i = i0 + q;
        if (i < N_NODES) rowptr[i] += add;
    }
}

__global__ __launch_bounds__(256) void k_fill(const int* __restrict__ src,
                                              const int* __restrict__ dst,
                                              int* __restrict__ rowptr,
                                              int* __restrict__ csr_src) {
    int e = blockIdx.x * blockDim.x + threadIdx.x;
    if (e < N_EDGES) {
        int p = atomicAdd(&rowptr[dst[e]], 1);
        csr_src[p] = src[e];
    }
}

// ---------------------------------------------------------------------------
// agg helpers: wave per node, 4 edges/iter; lane group g=lane>>4 takes edge
// base+g; its 16 lanes load 16B of the 256B bf16 featsh row.
// ---------------------------------------------------------------------------
__device__ __forceinline__ void agg_edge_dis(const char* outb,
                                             const float* dis,
                                             int s, int sub, float* acc) {
    float sc = dis[s];
    uint4 v = *(const uint4*)(outb + (size_t)s * 512 + 256 + sub * 16);
    acc[0] += bf2f(v.x & 0xffffu) * sc;
    acc[1] += bf2f(v.x >> 16) * sc;
    acc[2] += bf2f(v.y & 0xffffu) * sc;
    acc[3] += bf2f(v.y >> 16) * sc;
    acc[4] += bf2f(v.z & 0xffffu) * sc;
    acc[5] += bf2f(v.z >> 16) * sc;
    acc[6] += bf2f(v.w & 0xffffu) * sc;
    acc[7] += bf2f(v.w >> 16) * sc;
}

__device__ __forceinline__ void agg_edge_pk(const char* outb,
                                            const unsigned int* pk,
                                            int s, int sub, float* acc) {
    float sc = rsqrtf((float)(pk[s] & 0xffffu));
    uint4 v = *(const uint4*)(outb + (size_t)s * 512 + 256 + sub * 16);
    acc[0] += bf2f(v.x & 0xffffu) * sc;
    acc[1] += bf2f(v.x >> 16) * sc;
    acc[2] += bf2f(v.y & 0xffffu) * sc;
    acc[3] += bf2f(v.y >> 16) * sc;
    acc[4] += bf2f(v.z & 0xffffu) * sc;
    acc[5] += bf2f(v.z >> 16) * sc;
    acc[6] += bf2f(v.w & 0xffffu) * sc;
    acc[7] += bf2f(v.w >> 16) * sc;
}

__device__ __forceinline__ void agg_finish(char* outb, int wid, float scn,
                                           int grp, int sub, float* acc) {
#pragma unroll
    for (int i = 0; i < 8; i++) {
        acc[i] += __shfl_xor(acc[i], 16);
        acc[i] += __shfl_xor(acc[i], 32);
    }
    if (grp == 0) {
        uint4 p;
        p.x = (unsigned)f2bf(acc[0] * scn) | ((unsigned)f2bf(acc[1] * scn) << 16);
        p.y = (unsigned)f2bf(acc[2] * scn) | ((unsigned)f2bf(acc[3] * scn) << 16);
        p.z = (unsigned)f2bf(acc[4] * scn) | ((unsigned)f2bf(acc[5] * scn) << 16);
        p.w = (unsigned)f2bf(acc[6] * scn) | ((unsigned)f2bf(acc[7] * scn) << 16);
        *(uint4*)(outb + (size_t)wid * 512 + sub * 16) = p;
    }
}

// Path A: bucket-indexed aggregation (+ rare overflow scan); dis[] based
__global__ __launch_bounds__(256) void k_agg_bkt(char* __restrict__ outb,
                                                 const unsigned int* __restrict__ pk,
                                                 const float* __restrict__ dis,
                                                 const int* __restrict__ bucket,
                                                 const int* __restrict__ ovf_cnt,
                                                 const int2* __restrict__ ovf) {
    int wid = (int)((blockIdx.x * (unsigned)blockDim.x + threadIdx.x) >> 6);
    int lane = threadIdx.x & 63;
    if (wid >= N_NODES) return;
    int grp = lane >> 4;
    int sub = lane & 15;
    int cnt = (int)pk[wid];
    int m = cnt < BKT_C ? cnt : BKT_C;
    const int* bk = bucket + wid * BKT_C;
    float acc[8];
#pragma unroll
    for (int i = 0; i < 8; i++) acc[i] = 0.f;

    for (int base = 0; base < m; base += 4) {
        int e = base + grp;
        if (e < m) agg_edge_dis(outb, dis, bk[e], sub, acc);
    }
    if (cnt > BKT_C) {   // rare: scan tiny overflow list
        int no = *ovf_cnt;
        if (no > OVF_CAP) no = OVF_CAP;
        for (int i = grp; i < no; i += 4) {
            int2 p = ovf[i];
            if (p.x == wid) agg_edge_dis(outb, dis, p.y, sub, acc);
        }
    }
    agg_finish(outb, wid, dis[wid], grp, sub, acc);
}

// Path B: end-pointer CSR aggregation; pk-based normalization
__global__ __launch_bounds__(256) void k_agg_csr(char* __restrict__ outb,
                                                 const unsigned int* __restrict__ pk,
                                                 const int* __restrict__ rowptr,
                                                 const int* __restrict__ csr_src) {
    int wid = (int)((blockIdx.x * (unsigned)blockDim.x + threadIdx.x) >> 6);
    int lane = threadIdx.x & 63;
    if (wid >= N_NODES) return;
    int grp = lane >> 4;
    int sub = lane & 15;
    int start = (wid == 0) ? 0 : rowptr[wid - 1];
    int end = rowptr[wid];
    float acc[8];
#pragma unroll
    for (int i = 0; i < 8; i++) acc[i] = 0.f;
    for (int base = start; base < end; base += 4) {
        int e = base + grp;
        if (e < end) agg_edge_pk(outb, pk, csr_src[e], sub, acc);
    }
    int dsrc = (int)(pk[wid] & 0xffffu);
    float scn = (dsrc > 0) ? rsqrtf((float)dsrc) : 0.0f;
    agg_finish(outb, wid, scn, grp, sub, acc);
}

// ---------------------------------------------------------------------------
// k_gemm: out[n,:] = Arow[n] @ Bcat^T + bias, MFMA 16x16x32 bf16, K=256.
// Arow = packed [aggh|featsh] bf16 rows in d_out; overwritten in place with
// the fp32 result. Block: 128 rows, 4 waves; wave = 32 rows x 128 cols.
// ---------------------------------------------------------------------------
__global__ __launch_bounds__(256) void k_gemm(const unsigned short* __restrict__ Bcat,
                                              const float* __restrict__ bias,
                                              float* __restrict__ outf) {
    __shared__ unsigned short Bl[128][264];
    const char* Ab = (const char*)outf;
    int tid = threadIdx.x;
    int lane = tid & 63;
    int w = tid >> 6;
    int n0 = blockIdx.x * 128;

    for (int i = tid; i < 128 * 32; i += 256) {
        int r = i >> 5, c = i & 31;
        *(uint4*)(&Bl[r][c * 8]) = *(const uint4*)(Bcat + r * 256 + c * 8);
    }
    __syncthreads();

    int q = lane >> 4;
    int lr = lane & 15;

    int r0 = n0 + w * 32 + lr;      if (r0 > N_NODES - 1) r0 = N_NODES - 1;
    int r1 = n0 + w * 32 + 16 + lr; if (r1 > N_NODES - 1) r1 = N_NODES - 1;
    const char* a0p = Ab + (size_t)r0 * 512 + q * 16;
    const char* a1p = Ab + (size_t)r1 * 512 + q * 16;

    v4f acc[2][8];
#pragma unroll
    for (int mt = 0; mt < 2; mt++)
#pragma unroll
        for (int t = 0; t < 8; t++) acc[mt][t] = (v4f){0.f, 0.f, 0.f, 0.f};

#pragma unroll
    for (int kk = 0; kk < 8; kk++) {
        v8s a0 = *(const v8s*)(a0p + kk * 64);
        v8s a1 = *(const v8s*)(a1p + kk * 64);
#pragma unroll
        for (int t = 0; t < 8; t++) {
            v8s b = *(const v8s*)(&Bl[t * 16 + lr][kk * 32 + q * 8]);
            acc[0][t] = __builtin_amdgcn_mfma_f32_16x16x32_bf16(a0, b, acc[0][t], 0, 0, 0);
            acc[1][t] = __builtin_amdgcn_mfma_f32_16x16x32_bf16(a1, b, acc[1][t], 0, 0, 0);
        }
    }

#pragma unroll
    for (int t = 0; t < 8; t++) {
        float bv = bias[t * 16 + lr];
#pragma unroll
        for (int mt = 0; mt < 2; mt++) {
            int rowb = n0 + w * 32 + mt * 16 + q * 4;
#pragma unroll
            for (int r = 0; r < 4; r++) {
                int row = rowb + r;
                if (row < N_NODES)
                    outf[(size_t)row * 128 + t * 16 + lr] = acc[mt][t][r] + bv;
            }
        }
    }
}

// ---------------------------------------------------------------------------
extern "C" void kernel_launch(void* const* d_in, const int* in_sizes, int n_in,
                              void* d_out, int out_size, void* d_ws, size_t ws_size,
                              hipStream_t stream) {
    const float* feats = (const float*)d_in[0];
    const int*   src   = (const int*)d_in[1];
    const int*   dst   = (const int*)d_in[2];
    const float* Wskip = (const float*)d_in[3];
    const float* bskip = (const float*)d_in[4];
    const float* Wmsg  = (const float*)d_in[5];
    const float* bmsg  = (const float*)d_in[6];

    char* w = (char*)d_ws;

    // Path A layout (single-pass bucketing + atomic-free deg_src), 7,397,248 B:
    //   [0,      400000)  uint  pk[N]      (bucket-claim counts = cnt_dst)
    //   [400000, 800000)  float dis[N]
    //   [800000, 800128)  int   ovf_cnt (+pad)
    //   [800128, 865664)  ushort Bcat[128*256]
    //   [865664, 866176)  float bias[128]
    //   [866176,7266176)  int   bucket[N*16]   (aliased: partials[128*6250] u32
    //                                           in first 3.2 MB, dead after k_comb)
    //   [7266176,7397248) int2  ovf[16384]
    // Path B layout (R5 pipeline), 3,426,688 B.
    bool pathA = ws_size >= (size_t)7397248;

    if (pathA) {
        unsigned int*   pk       = (unsigned int*)w;
        float*          dis      = (float*)(w + 400000);
        int*            ovf_cnt  = (int*)(w + 800000);
        unsigned short* Bcat     = (unsigned short*)(w + 800128);
        float*          bias     = (float*)(w + 865664);
        int*            bucket   = (int*)(w + 866176);
        unsigned int*   partials = (unsigned int*)(w + 866176);
        int2*           ovf      = (int2*)(w + 7266176);

        hipLaunchKernelGGL(k_zero, dim3((N_NODES / 4 + 255) / 256), dim3(256), 0,
                           stream, (int4*)pk, ovf_cnt);
        hipLaunchKernelGGL(k_hist, dim3(NRG * NSL), dim3(1024), 0, stream, src,
                           partials);
        hipLaunchKernelGGL(k_comb, dim3((N_NODES + 255) / 256), dim3(256), 0, stream,
                           partials, dis);
        hipLaunchKernelGGL(k_pre, dim3((N_NODES * (D / 8) + 255) / 256), dim3(256),
                           0, stream, feats, Wmsg, Wskip, bmsg, bskip, src, dst, pk,
                           Bcat, bias, (char*)d_out, bucket, ovf_cnt, ovf);
        hipLaunchKernelGGL(k_agg_bkt, dim3((N_NODES * 64 + 255) / 256), dim3(256), 0,
                           stream, (char*)d_out, pk, dis, bucket, ovf_cnt, ovf);
        hipLaunchKernelGGL(k_gemm, dim3((N_NODES + 127) / 128), dim3(256), 0, stream,
                           Bcat, bias, (float*)d_out);
    } else {
        unsigned int*   pk      = (unsigned int*)w;
        int*            rowptr  = (int*)(w + 400000);
        int*            bsums   = (int*)(w + 800128);
        unsigned short* Bcat    = (unsigned short*)(w + 800640);
        float*          bias    = (float*)(w + 866176);
        int*            csr_src = (int*)(w + 866688);

        hipLaunchKernelGGL(k_zero, dim3((N_NODES / 4 + 255) / 256), dim3(256), 0,
                           stream, (int4*)pk, (int*)(w + 400000));
        hipLaunchKernelGGL(k_pre, dim3((N_NODES * (D / 8) + 255) / 256), dim3(256),
                           0, stream, feats, Wmsg, Wskip, bmsg, bskip, src, dst, pk,
                           Bcat, bias, (char*)d_out, (int*)nullptr, (int*)nullptr,
                           (int2*)nullptr);
        hipLaunchKernelGGL(k_scan1, dim3(NB), dim3(256), 0, stream, pk, rowptr,
                           bsums);
        hipLaunchKernelGGL(k_scan2, dim3(1), dim3(128), 0, stream, bsums);
        hipLaunchKernelGGL(k_scan3, dim3(NB), dim3(256), 0, stream, bsums, rowptr);
        hipLaunchKernelGGL(k_fill, dim3((N_EDGES + 255) / 256), dim3(256), 0, stream,
                           src, dst, rowptr, csr_src);
        hipLaunchKernelGGL(k_agg_csr, dim3((N_NODES * 64 + 255) / 256), dim3(256), 0,
                           stream, (char*)d_out, pk, rowptr, csr_src);
        hipLaunchKernelGGL(k_gemm, dim3((N_NODES + 127) / 128), dim3(256), 0, stream,
                           Bcat, bias, (float*)d_out);
    }
}